// Round 17
// baseline (66.208 us; speedup 1.0000x reference)
//
#include <hip/hip_runtime.h>
#include <stdint.h>

#define HW 4096
#define CH 256
#define NB 4

typedef __attribute__((ext_vector_type(8))) short bf16x8;
typedef __attribute__((ext_vector_type(4))) float f32x4;
typedef __attribute__((ext_vector_type(2))) long longx2;
typedef unsigned char u8;

__device__ __forceinline__ ushort f2bf(float f) {
    uint32_t u = __float_as_uint(f);
    u += 0x7fffu + ((u >> 16) & 1u);   // RNE
    return (ushort)(u >> 16);
}
// monotone float<->uint key (handles negatives) for atomicMax reductions
__device__ __forceinline__ uint fkey(float f) {
    uint b = __float_as_uint(f);
    return ((int)b < 0) ? ~b : (b | 0x80000000u);
}
__device__ __forceinline__ float finv(uint k) {
    uint b = (k & 0x80000000u) ? (k ^ 0x80000000u) : ~k;
    return __uint_as_float(b);
}
// force a value to stay materialized in VGPRs (defeats rematerialization)
__device__ __forceinline__ void keepl(longx2& v) { asm volatile("" : "+v"(v)); }

// raw barrier: LDS-ordering only, does NOT drain vmcnt (keeps prefetch alive)
#define LGK_BAR()                                                        \
    do {                                                                 \
        asm volatile("s_waitcnt lgkmcnt(0)" ::: "memory");               \
        __builtin_amdgcn_sched_barrier(0);                               \
        asm volatile("s_barrier" ::: "memory");                          \
    } while (0)

// fp8 fragment-PAIR index (scores operands): lane's 16B = 8B even frag ||
// 8B odd frag, so one dwordx4 wave-load feeds TWO MFMA operands.
__device__ __forceinline__ size_t fragidx(int b, int o, int hw) {
    return ((((size_t)b * 8 + (o >> 5)) * 128 + (hw >> 5)) * 1024)
         + ((((o >> 3) & 3) * 16 + (hw & 15)) * 16)
         + (((hw >> 4) & 1) * 8) + (o & 7);
}
// bf16 A-fragment-packed weight index (conv A operands): block
// (c>>5, o>>4) is 1KB contiguous; lane = ((c>>3)&3)*16 + (o&15), elem c&7.
__device__ __forceinline__ int wpackidx(int o, int c) {
    return (((c >> 5) * 16 + (o >> 4)) * 64 + ((c >> 3) & 3) * 16 + (o & 15)) * 8
         + (c & 7);
}

// ---------------------------------------------------------------------------
// prep: weights fp32 -> bf16 in A-FRAGMENT-PACKED order; zero m2/Qmask keys
__global__ __launch_bounds__(256) void prep_kernel(
    const float* __restrict__ Wq, const float* __restrict__ Wk,
    const float* __restrict__ Wv,
    ushort* __restrict__ Wq16, ushort* __restrict__ Wk16,
    ushort* __restrict__ Wv16, unsigned int* __restrict__ m2k,
    unsigned int* __restrict__ qmk) {
    int i = blockIdx.x * 256 + threadIdx.x;   // grid covers 65536
    int o = i >> 8, c = i & 255;
    int idx = wpackidx(o, c);
    Wq16[idx] = f2bf(Wq[i]);
    Wk16[idx] = f2bf(Wk[i]);
    Wv16[idx] = f2bf(Wv[i]);
    if (i < NB * HW) qmk[i] = 0;              // fkey-min
    if (i < NB * 64) m2k[i] = 0;              // positive-float-min
}

// ---------------------------------------------------------------------------
// Fused Q+K conv1x1: hw tile 32 (grid 512 -> 2 blocks/CU), weights via
// DIRECT coalesced global loads from packed layout (no weight LDS).
// LDS: tileF(8.4K) + Bls(4.6K), qred aliases tileF -> ~13KB total.
__global__ __launch_bounds__(256, 2) void convQK_kernel(
    const float* __restrict__ fuse,
    const ushort* __restrict__ Wq16, const ushort* __restrict__ Wk16,
    const float* __restrict__ bq, const float* __restrict__ bk,
    u8* __restrict__ Qw8, u8* __restrict__ Kw8,
    unsigned int* __restrict__ qmout) {
    __shared__ __align__(16) char cpool[13056];
    float (*tileF)[33]   = (float(*)[33])cpool;             // [64][33] f32
    ushort (*Bls)[72]    = (ushort(*)[72])(cpool + 8448);   // [32][72]
    float (*qred)[4][32] = (float(*)[4][32])cpool;          // alias tileF
    const int t = threadIdx.x;
    const int lane = t & 63, w = t >> 6;
    const int hw0 = blockIdx.x * 32;
    const int b = blockIdx.y;
    f32x4 accQ[4][2] = {}, accK[4][2] = {};   // [rf(o)][cf(hw)]
    for (int kc = 0; kc < 4; ++kc) {
        __syncthreads();
        {   // stage fuse[b][kc*64+c][hw0..32] -> tileF[c][hw]
            const int c = t >> 2, h8 = (t & 3) * 8;
            const float* src = fuse + ((size_t)b * CH + kc * 64 + c) * HW + hw0 + h8;
            #pragma unroll
            for (int q = 0; q < 2; ++q) {
                float4 v = *(const float4*)(src + q * 4);
                tileF[c][h8 + q * 4 + 0] = v.x; tileF[c][h8 + q * 4 + 1] = v.y;
                tileF[c][h8 + q * 4 + 2] = v.z; tileF[c][h8 + q * 4 + 3] = v.w;
            }
        }
        __syncthreads();
        {   // tileF -> Bls[hw][c] bf16 (transposed)
            const int hw = t >> 3, i8 = (t & 7) * 8;
            __align__(16) ushort o8[8];
            #pragma unroll
            for (int k = 0; k < 8; ++k) o8[k] = f2bf(tileF[i8 + k][hw]);
            *(int4*)&Bls[hw][i8] = *(const int4*)o8;
        }
        __syncthreads();
        #pragma unroll
        for (int kk = 0; kk < 2; ++kk) {
            bf16x8 aq[4], ak[4];
            const int fb = ((kc * 2 + kk) * 16 + w * 4) * 512 + lane * 8;
            #pragma unroll
            for (int rf = 0; rf < 4; ++rf) {
                aq[rf] = *(const bf16x8*)(Wq16 + fb + rf * 512);
                ak[rf] = *(const bf16x8*)(Wk16 + fb + rf * 512);
            }
            #pragma unroll
            for (int cf = 0; cf < 2; ++cf) {
                bf16x8 bf_ = *(const bf16x8*)&Bls[cf * 16 + (lane & 15)]
                                                 [kk * 32 + (lane >> 4) * 8];
                #pragma unroll
                for (int rf = 0; rf < 4; ++rf) {
                    accQ[rf][cf] = __builtin_amdgcn_mfma_f32_16x16x32_bf16(
                        aq[rf], bf_, accQ[rf][cf], 0, 0, 0);
                    accK[rf][cf] = __builtin_amdgcn_mfma_f32_16x16x32_bf16(
                        ak[rf], bf_, accK[rf][cf], 0, 0, 0);
                }
            }
        }
    }
    float qmx[2][4];   // [cf][r] running max for Q_mask
    #pragma unroll
    for (int cf = 0; cf < 2; ++cf)
        #pragma unroll
        for (int r = 0; r < 4; ++r) qmx[cf][r] = -3.4e38f;
    #pragma unroll
    for (int rf = 0; rf < 4; ++rf) {
        const int ob = w * 64 + rf * 16 + (lane >> 4) * 4;  // o base (mult of 4)
        #pragma unroll
        for (int cf = 0; cf < 2; ++cf) {
            const int hw = hw0 + cf * 16 + (lane & 15);
            size_t idx = fragidx(b, ob, hw);
            {   // Q
                float v0 = accQ[rf][cf][0] + bq[ob + 0];
                float v1 = accQ[rf][cf][1] + bq[ob + 1];
                float v2 = accQ[rf][cf][2] + bq[ob + 2];
                float v3 = accQ[rf][cf][3] + bq[ob + 3];
                int u = __builtin_amdgcn_cvt_pk_fp8_f32(v0, v1, 0, false);
                u = __builtin_amdgcn_cvt_pk_fp8_f32(v2, v3, u, true);
                *(unsigned int*)&Qw8[idx] = (unsigned int)u;
                qmx[cf][0] = fmaxf(qmx[cf][0], v0);
                qmx[cf][1] = fmaxf(qmx[cf][1], v1);
                qmx[cf][2] = fmaxf(qmx[cf][2], v2);
                qmx[cf][3] = fmaxf(qmx[cf][3], v3);
            }
            {   // K
                float v0 = accK[rf][cf][0] + bk[ob + 0];
                float v1 = accK[rf][cf][1] + bk[ob + 1];
                float v2 = accK[rf][cf][2] + bk[ob + 2];
                float v3 = accK[rf][cf][3] + bk[ob + 3];
                int u = __builtin_amdgcn_cvt_pk_fp8_f32(v0, v1, 0, false);
                u = __builtin_amdgcn_cvt_pk_fp8_f32(v2, v3, u, true);
                *(unsigned int*)&Kw8[idx] = (unsigned int)u;
            }
        }
    }
    // Q_mask reduce: lanes l, l^16, l^32, l^48 share hw col & class r
    #pragma unroll
    for (int cf = 0; cf < 2; ++cf)
        #pragma unroll
        for (int r = 0; r < 4; ++r) {
            float v = qmx[cf][r];
            v = fmaxf(v, __shfl_xor(v, 16));
            v = fmaxf(v, __shfl_xor(v, 32));
            qmx[cf][r] = v;
        }
    __syncthreads();   // last tileF read long done; qred aliases it
    if (lane < 16) {
        #pragma unroll
        for (int cf = 0; cf < 2; ++cf)
            #pragma unroll
            for (int r = 0; r < 4; ++r)
                qred[w][r][cf * 16 + lane] = qmx[cf][r];
    }
    __syncthreads();
    if (t < 128) {
        const int r = t >> 5, h = t & 31;
        float v = fmaxf(fmaxf(qred[0][r][h], qred[1][r][h]),
                        fmaxf(qred[2][r][h], qred[3][r][h]));
        atomicMax(qmout + r * HW + hw0 + h, fkey(v));
    }
}

// ---------------------------------------------------------------------------
// V conv + mask epilogue: same hw-32 tiling + direct packed-weight loads.
__global__ __launch_bounds__(256, 2) void convV_kernel(
    const float* __restrict__ fuse, const ushort* __restrict__ Wv16,
    const float* __restrict__ bv, float* __restrict__ outf,
    const unsigned int* __restrict__ m2key,
    const unsigned int* __restrict__ qmkey) {
    __shared__ __align__(16) char cpool[13056];
    float (*tileF)[33] = (float(*)[33])cpool;
    ushort (*Bls)[72]  = (ushort(*)[72])(cpool + 8448);
    __shared__ float m2s[64];
    const int t = threadIdx.x;
    const int lane = t & 63, w = t >> 6;
    const int hw0 = blockIdx.x * 32;
    const int b = blockIdx.y;
    if (t < 64) m2s[t] = __uint_as_float(m2key[b * 64 + t]);
    f32x4 acc[4][2] = {};
    for (int kc = 0; kc < 4; ++kc) {
        __syncthreads();
        {
            const int c = t >> 2, h8 = (t & 3) * 8;
            const float* src = fuse + ((size_t)b * CH + kc * 64 + c) * HW + hw0 + h8;
            #pragma unroll
            for (int q = 0; q < 2; ++q) {
                float4 v = *(const float4*)(src + q * 4);
                tileF[c][h8 + q * 4 + 0] = v.x; tileF[c][h8 + q * 4 + 1] = v.y;
                tileF[c][h8 + q * 4 + 2] = v.z; tileF[c][h8 + q * 4 + 3] = v.w;
            }
        }
        __syncthreads();
        {
            const int hw = t >> 3, i8 = (t & 7) * 8;
            __align__(16) ushort o8[8];
            #pragma unroll
            for (int k = 0; k < 8; ++k) o8[k] = f2bf(tileF[i8 + k][hw]);
            *(int4*)&Bls[hw][i8] = *(const int4*)o8;
        }
        __syncthreads();
        #pragma unroll
        for (int kk = 0; kk < 2; ++kk) {
            bf16x8 af[4];
            const int fb = ((kc * 2 + kk) * 16 + w * 4) * 512 + lane * 8;
            #pragma unroll
            for (int rf = 0; rf < 4; ++rf)
                af[rf] = *(const bf16x8*)(Wv16 + fb + rf * 512);
            #pragma unroll
            for (int cf = 0; cf < 2; ++cf) {
                bf16x8 bf_ = *(const bf16x8*)&Bls[cf * 16 + (lane & 15)]
                                                 [kk * 32 + (lane >> 4) * 8];
                #pragma unroll
                for (int rf = 0; rf < 4; ++rf)
                    acc[rf][cf] = __builtin_amdgcn_mfma_f32_16x16x32_bf16(
                        af[rf], bf_, acc[rf][cf], 0, 0, 0);
            }
        }
    }
    #pragma unroll
    for (int rf = 0; rf < 4; ++rf) {
        const int ob = w * 64 + rf * 16 + (lane >> 4) * 4;
        #pragma unroll
        for (int cf = 0; cf < 2; ++cf) {
            const int hw = hw0 + cf * 16 + (lane & 15);
            const float mv = m2s[ob >> 2];
            #pragma unroll
            for (int r = 0; r < 4; ++r) {   // o = ob+r, o%4 == r
                float vv = acc[rf][cf][r] + bv[ob + r];
                float qm = finv(qmkey[r * HW + hw]);
                outf[((size_t)b * CH + ob + r) * HW + hw] = vv * (1.0f + mv * qm);
            }
        }
    }
}

// ---------------------------------------------------------------------------
// scores64 persistent m-strip. R17: amdgpu_waves_per_eu(2,2) pins the MAX
// occupancy at the residency we already run (2 blocks/CU), removing the
// allocator's incentive to economize registers below the 256 budget --
// R15/R16 it stopped at 124-128 VGPR and rematerialized the AQ loads
// (FETCH +50%). Expect VGPR >= 180 and FETCH back to ~12.5 MB.
__global__ __launch_bounds__(256)
__attribute__((amdgpu_waves_per_eu(2, 2))) void scores64(
    const u8* __restrict__ Qw, const u8* __restrict__ Kw,
    unsigned int* __restrict__ m2k) {
    __shared__ __align__(16) f32x4 EX[4][4][4][64];   // [b][nf][mf][lane] 64 KB
    __shared__ float red[4][4];                       // [wave][batch]
    const int t = threadIdx.x;
    const int lane = t & 63, w = t >> 6;              // w = batch
    const int bid = blockIdx.x;
    const int xcd = bid & 7, j = bid >> 3;
    const int vm = xcd * 8 + (j & 7);
    const int s  = j >> 3;                            // n-strip: vn = s*8+it

    const u8* kp  = Kw + (((size_t)w * 8) * 128 + vm * 2) * 1024 + lane * 16;
    const u8* qp0 = Qw + (((size_t)w * 8) * 128 + (s * 8) * 2) * 1024 + lane * 16;

    // K resident for the whole strip
    longx2 BK[8][2];
    #pragma unroll
    for (int kc = 0; kc < 8; ++kc)
        #pragma unroll
        for (int p = 0; p < 2; ++p)
            BK[kc][p] = *(const longx2*)(kp + (size_t)kc * 131072 + p * 1024);
    #pragma unroll
    for (int kc = 0; kc < 8; ++kc)
        #pragma unroll
        for (int p = 0; p < 2; ++p) keepl(BK[kc][p]);

    longx2 AQ[8][2];
#define LOADQ(IT)                                                          \
    _Pragma("unroll") for (int kc = 0; kc < 8; ++kc)                       \
        _Pragma("unroll") for (int p = 0; p < 2; ++p)                      \
            AQ[kc][p] = *(const longx2*)(qp0 + (IT) * 2048                 \
                                         + (size_t)kc * 131072 + p * 1024);
#define KEEPQ()                                                            \
    _Pragma("unroll") for (int kc = 0; kc < 8; ++kc)                       \
        _Pragma("unroll") for (int p = 0; p < 2; ++p) keepl(AQ[kc][p]);
    LOADQ(0)

    float pmAll[4] = {0.f, 0.f, 0.f, 0.f};
    #pragma unroll
    for (int it = 0; it < 8; ++it) {
        KEEPQ()   // materialize the prefetched tile (waitcnt lands here)
        f32x4 acc[4][4] = {};   // [nf][mf]
        #pragma unroll
        for (int kc = 0; kc < 8; ++kc) {
            #pragma unroll
            for (int mf = 0; mf < 4; ++mf) {
                long bf_ = BK[kc][mf >> 1][mf & 1];
                #pragma unroll
                for (int nf = 0; nf < 4; ++nf)
                    acc[nf][mf] = __builtin_amdgcn_mfma_f32_16x16x32_fp8_fp8(
                        AQ[kc][nf >> 1][nf & 1], bf_, acc[nf][mf], 0, 0, 0);
            }
        }
        // prefetch next tile's Q; stays in flight across the raw barriers
        if (it + 1 < 8) { LOADQ(it + 1) }

        if (it) LGK_BAR();                // prev tile's EX reads done everywhere
        #pragma unroll
        for (int nf = 0; nf < 4; ++nf)
            #pragma unroll
            for (int mf = 0; mf < 4; ++mf)
                EX[w][nf][mf][lane] = acc[nf][mf];
        LGK_BAR();                        // all EX writes visible
        #pragma unroll
        for (int nf = 0; nf < 4; ++nf) {
            f32x4 sv[4];
            #pragma unroll
            for (int b2 = 0; b2 < 4; ++b2)
                sv[b2] = EX[b2][nf][w][lane];   // this thread owns mf = w
            #pragma unroll
            for (int jj = 0; jj < 4; ++jj) {
                float e0 = __expf(sv[0][jj] * 0.0625f);
                float e1 = __expf(sv[1][jj] * 0.0625f);
                float e2 = __expf(sv[2][jj] * 0.0625f);
                float e3 = __expf(sv[3][jj] * 0.0625f);
                float inv = __fdividef(1.0f, e0 + e1 + e2 + e3);
                pmAll[0] = fmaxf(pmAll[0], e0 * inv);
                pmAll[1] = fmaxf(pmAll[1], e1 * inv);
                pmAll[2] = fmaxf(pmAll[2], e2 * inv);
                pmAll[3] = fmaxf(pmAll[3], e3 * inv);
            }
        }
    }
#undef LOADQ
#undef KEEPQ
    // strip-wide reduce: wave max, block max, ONE atomic per batch
    #pragma unroll
    for (int off = 32; off >= 1; off >>= 1) {
        pmAll[0] = fmaxf(pmAll[0], __shfl_xor(pmAll[0], off));
        pmAll[1] = fmaxf(pmAll[1], __shfl_xor(pmAll[1], off));
        pmAll[2] = fmaxf(pmAll[2], __shfl_xor(pmAll[2], off));
        pmAll[3] = fmaxf(pmAll[3], __shfl_xor(pmAll[3], off));
    }
    __syncthreads();
    if (lane == 0) {
        #pragma unroll
        for (int b2 = 0; b2 < 4; ++b2) red[w][b2] = pmAll[b2];
    }
    __syncthreads();
    if (t < 4) {   // t = batch
        float v = fmaxf(fmaxf(red[0][t], red[1][t]),
                        fmaxf(red[2][t], red[3][t]));
        atomicMax(m2k + t * 64 + vm, __float_as_uint(v));  // soft > 0
    }
}

// ---------------------------------------------------------------------------
extern "C" void kernel_launch(void* const* d_in, const int* in_sizes, int n_in,
                              void* d_out, int out_size, void* d_ws, size_t ws_size,
                              hipStream_t stream) {
    const float* fuse = (const float*)d_in[0];
    const float* Wq   = (const float*)d_in[1];
    const float* bq   = (const float*)d_in[2];
    const float* Wk   = (const float*)d_in[3];
    const float* bk   = (const float*)d_in[4];
    const float* Wv   = (const float*)d_in[5];
    const float* bv   = (const float*)d_in[6];
    float* out = (float*)d_out;

    char* ws = (char*)d_ws;
    ushort* Wq16  = (ushort*)(ws);                      // 128 KiB (A-frag packed)
    ushort* Wk16  = (ushort*)(ws + 131072);             // 128 KiB
    ushort* Wv16  = (ushort*)(ws + 262144);             // 128 KiB
    u8*     Qw8   = (u8*)    (ws + 393216);             // 4 MiB (fp8 pair-frag)
    u8*     Kw8   = (u8*)    (ws + 4587520);            // 4 MiB (fp8 pair-frag)
    unsigned int* QMK = (unsigned int*)(ws + 8781824);  // 64 KiB (Q_mask keys)
    unsigned int* M2K = (unsigned int*)(ws + 8847360);  // 1 KiB (m2 keys)

    prep_kernel<<<256, 256, 0, stream>>>(Wq, Wk, Wv, Wq16, Wk16, Wv16, M2K, QMK);
    convQK_kernel<<<dim3(128, NB), 256, 0, stream>>>(
        fuse, Wq16, Wk16, bq, bk, Qw8, Kw8, QMK);
    scores64<<<512, 256, 0, stream>>>(Qw8, Kw8, M2K);
    convV_kernel<<<dim3(128, NB), 256, 0, stream>>>(
        fuse, Wv16, bv, out, M2K, QMK);
}

// Round 18
// 65.668 us; speedup vs baseline: 1.0082x; 1.0082x over previous
//
#include <hip/hip_runtime.h>
#include <stdint.h>

#define HW 4096
#define CH 256
#define NB 4

typedef __attribute__((ext_vector_type(8))) short bf16x8;
typedef __attribute__((ext_vector_type(4))) float f32x4;
typedef __attribute__((ext_vector_type(2))) long longx2;
typedef unsigned char u8;

__device__ __forceinline__ ushort f2bf(float f) {
    uint32_t u = __float_as_uint(f);
    u += 0x7fffu + ((u >> 16) & 1u);   // RNE
    return (ushort)(u >> 16);
}
// monotone float<->uint key (handles negatives) for atomicMax reductions
__device__ __forceinline__ uint fkey(float f) {
    uint b = __float_as_uint(f);
    return ((int)b < 0) ? ~b : (b | 0x80000000u);
}
__device__ __forceinline__ float finv(uint k) {
    uint b = (k & 0x80000000u) ? (k ^ 0x80000000u) : ~k;
    return __uint_as_float(b);
}

// inline-asm 16B global load: NOT rematerializable, NOT reorderable past
// other volatile asm -- forces true register residency of the destination.
// Reader MUST execute s_waitcnt vmcnt(N) (asm) before consuming the result.
__device__ __forceinline__ void gload16(longx2& r, const u8* p) {
    asm volatile("global_load_dwordx4 %0, %1, off"
                 : "=v"(r) : "v"(p) : "memory");
}

// raw barrier: LDS-ordering only, does NOT drain vmcnt (keeps prefetch alive)
#define LGK_BAR()                                                        \
    do {                                                                 \
        asm volatile("s_waitcnt lgkmcnt(0)" ::: "memory");               \
        __builtin_amdgcn_sched_barrier(0);                               \
        asm volatile("s_barrier" ::: "memory");                          \
    } while (0)

// fp8 fragment-PAIR index (scores operands): lane's 16B = 8B even frag ||
// 8B odd frag, so one dwordx4 wave-load feeds TWO MFMA operands.
__device__ __forceinline__ size_t fragidx(int b, int o, int hw) {
    return ((((size_t)b * 8 + (o >> 5)) * 128 + (hw >> 5)) * 1024)
         + ((((o >> 3) & 3) * 16 + (hw & 15)) * 16)
         + (((hw >> 4) & 1) * 8) + (o & 7);
}
// bf16 A-fragment-packed weight index (conv A operands): block
// (c>>5, o>>4) is 1KB contiguous; lane = ((c>>3)&3)*16 + (o&15), elem c&7.
__device__ __forceinline__ int wpackidx(int o, int c) {
    return (((c >> 5) * 16 + (o >> 4)) * 64 + ((c >> 3) & 3) * 16 + (o & 15)) * 8
         + (c & 7);
}

// ---------------------------------------------------------------------------
// prep: weights fp32 -> bf16 in A-FRAGMENT-PACKED order; zero m2/Qmask keys
__global__ __launch_bounds__(256) void prep_kernel(
    const float* __restrict__ Wq, const float* __restrict__ Wk,
    const float* __restrict__ Wv,
    ushort* __restrict__ Wq16, ushort* __restrict__ Wk16,
    ushort* __restrict__ Wv16, unsigned int* __restrict__ m2k,
    unsigned int* __restrict__ qmk) {
    int i = blockIdx.x * 256 + threadIdx.x;   // grid covers 65536
    int o = i >> 8, c = i & 255;
    int idx = wpackidx(o, c);
    Wq16[idx] = f2bf(Wq[i]);
    Wk16[idx] = f2bf(Wk[i]);
    Wv16[idx] = f2bf(Wv[i]);
    if (i < NB * HW) qmk[i] = 0;              // fkey-min
    if (i < NB * 64) m2k[i] = 0;              // positive-float-min
}

// ---------------------------------------------------------------------------
// Fused Q+K conv1x1: hw tile 32 (grid 512 -> 2 blocks/CU), weights via
// DIRECT coalesced global loads from packed layout (no weight LDS).
// LDS: tileF(8.4K) + Bls(4.6K), qred aliases tileF -> ~13KB total.
__global__ __launch_bounds__(256, 2) void convQK_kernel(
    const float* __restrict__ fuse,
    const ushort* __restrict__ Wq16, const ushort* __restrict__ Wk16,
    const float* __restrict__ bq, const float* __restrict__ bk,
    u8* __restrict__ Qw8, u8* __restrict__ Kw8,
    unsigned int* __restrict__ qmout) {
    __shared__ __align__(16) char cpool[13056];
    float (*tileF)[33]   = (float(*)[33])cpool;             // [64][33] f32
    ushort (*Bls)[72]    = (ushort(*)[72])(cpool + 8448);   // [32][72]
    float (*qred)[4][32] = (float(*)[4][32])cpool;          // alias tileF
    const int t = threadIdx.x;
    const int lane = t & 63, w = t >> 6;
    const int hw0 = blockIdx.x * 32;
    const int b = blockIdx.y;
    f32x4 accQ[4][2] = {}, accK[4][2] = {};   // [rf(o)][cf(hw)]
    for (int kc = 0; kc < 4; ++kc) {
        __syncthreads();
        {   // stage fuse[b][kc*64+c][hw0..32] -> tileF[c][hw]
            const int c = t >> 2, h8 = (t & 3) * 8;
            const float* src = fuse + ((size_t)b * CH + kc * 64 + c) * HW + hw0 + h8;
            #pragma unroll
            for (int q = 0; q < 2; ++q) {
                float4 v = *(const float4*)(src + q * 4);
                tileF[c][h8 + q * 4 + 0] = v.x; tileF[c][h8 + q * 4 + 1] = v.y;
                tileF[c][h8 + q * 4 + 2] = v.z; tileF[c][h8 + q * 4 + 3] = v.w;
            }
        }
        __syncthreads();
        {   // tileF -> Bls[hw][c] bf16 (transposed)
            const int hw = t >> 3, i8 = (t & 7) * 8;
            __align__(16) ushort o8[8];
            #pragma unroll
            for (int k = 0; k < 8; ++k) o8[k] = f2bf(tileF[i8 + k][hw]);
            *(int4*)&Bls[hw][i8] = *(const int4*)o8;
        }
        __syncthreads();
        #pragma unroll
        for (int kk = 0; kk < 2; ++kk) {
            bf16x8 aq[4], ak[4];
            const int fb = ((kc * 2 + kk) * 16 + w * 4) * 512 + lane * 8;
            #pragma unroll
            for (int rf = 0; rf < 4; ++rf) {
                aq[rf] = *(const bf16x8*)(Wq16 + fb + rf * 512);
                ak[rf] = *(const bf16x8*)(Wk16 + fb + rf * 512);
            }
            #pragma unroll
            for (int cf = 0; cf < 2; ++cf) {
                bf16x8 bf_ = *(const bf16x8*)&Bls[cf * 16 + (lane & 15)]
                                                 [kk * 32 + (lane >> 4) * 8];
                #pragma unroll
                for (int rf = 0; rf < 4; ++rf) {
                    accQ[rf][cf] = __builtin_amdgcn_mfma_f32_16x16x32_bf16(
                        aq[rf], bf_, accQ[rf][cf], 0, 0, 0);
                    accK[rf][cf] = __builtin_amdgcn_mfma_f32_16x16x32_bf16(
                        ak[rf], bf_, accK[rf][cf], 0, 0, 0);
                }
            }
        }
    }
    float qmx[2][4];   // [cf][r] running max for Q_mask
    #pragma unroll
    for (int cf = 0; cf < 2; ++cf)
        #pragma unroll
        for (int r = 0; r < 4; ++r) qmx[cf][r] = -3.4e38f;
    #pragma unroll
    for (int rf = 0; rf < 4; ++rf) {
        const int ob = w * 64 + rf * 16 + (lane >> 4) * 4;  // o base (mult of 4)
        #pragma unroll
        for (int cf = 0; cf < 2; ++cf) {
            const int hw = hw0 + cf * 16 + (lane & 15);
            size_t idx = fragidx(b, ob, hw);
            {   // Q
                float v0 = accQ[rf][cf][0] + bq[ob + 0];
                float v1 = accQ[rf][cf][1] + bq[ob + 1];
                float v2 = accQ[rf][cf][2] + bq[ob + 2];
                float v3 = accQ[rf][cf][3] + bq[ob + 3];
                int u = __builtin_amdgcn_cvt_pk_fp8_f32(v0, v1, 0, false);
                u = __builtin_amdgcn_cvt_pk_fp8_f32(v2, v3, u, true);
                *(unsigned int*)&Qw8[idx] = (unsigned int)u;
                qmx[cf][0] = fmaxf(qmx[cf][0], v0);
                qmx[cf][1] = fmaxf(qmx[cf][1], v1);
                qmx[cf][2] = fmaxf(qmx[cf][2], v2);
                qmx[cf][3] = fmaxf(qmx[cf][3], v3);
            }
            {   // K
                float v0 = accK[rf][cf][0] + bk[ob + 0];
                float v1 = accK[rf][cf][1] + bk[ob + 1];
                float v2 = accK[rf][cf][2] + bk[ob + 2];
                float v3 = accK[rf][cf][3] + bk[ob + 3];
                int u = __builtin_amdgcn_cvt_pk_fp8_f32(v0, v1, 0, false);
                u = __builtin_amdgcn_cvt_pk_fp8_f32(v2, v3, u, true);
                *(unsigned int*)&Kw8[idx] = (unsigned int)u;
            }
        }
    }
    // Q_mask reduce: lanes l, l^16, l^32, l^48 share hw col & class r
    #pragma unroll
    for (int cf = 0; cf < 2; ++cf)
        #pragma unroll
        for (int r = 0; r < 4; ++r) {
            float v = qmx[cf][r];
            v = fmaxf(v, __shfl_xor(v, 16));
            v = fmaxf(v, __shfl_xor(v, 32));
            qmx[cf][r] = v;
        }
    __syncthreads();   // last tileF read long done; qred aliases it
    if (lane < 16) {
        #pragma unroll
        for (int cf = 0; cf < 2; ++cf)
            #pragma unroll
            for (int r = 0; r < 4; ++r)
                qred[w][r][cf * 16 + lane] = qmx[cf][r];
    }
    __syncthreads();
    if (t < 128) {
        const int r = t >> 5, h = t & 31;
        float v = fmaxf(fmaxf(qred[0][r][h], qred[1][r][h]),
                        fmaxf(qred[2][r][h], qred[3][r][h]));
        atomicMax(qmout + r * HW + hw0 + h, fkey(v));
    }
}

// ---------------------------------------------------------------------------
// V conv + mask epilogue: same hw-32 tiling + direct packed-weight loads.
__global__ __launch_bounds__(256, 2) void convV_kernel(
    const float* __restrict__ fuse, const ushort* __restrict__ Wv16,
    const float* __restrict__ bv, float* __restrict__ outf,
    const unsigned int* __restrict__ m2key,
    const unsigned int* __restrict__ qmkey) {
    __shared__ __align__(16) char cpool[13056];
    float (*tileF)[33] = (float(*)[33])cpool;
    ushort (*Bls)[72]  = (ushort(*)[72])(cpool + 8448);
    __shared__ float m2s[64];
    const int t = threadIdx.x;
    const int lane = t & 63, w = t >> 6;
    const int hw0 = blockIdx.x * 32;
    const int b = blockIdx.y;
    if (t < 64) m2s[t] = __uint_as_float(m2key[b * 64 + t]);
    f32x4 acc[4][2] = {};
    for (int kc = 0; kc < 4; ++kc) {
        __syncthreads();
        {
            const int c = t >> 2, h8 = (t & 3) * 8;
            const float* src = fuse + ((size_t)b * CH + kc * 64 + c) * HW + hw0 + h8;
            #pragma unroll
            for (int q = 0; q < 2; ++q) {
                float4 v = *(const float4*)(src + q * 4);
                tileF[c][h8 + q * 4 + 0] = v.x; tileF[c][h8 + q * 4 + 1] = v.y;
                tileF[c][h8 + q * 4 + 2] = v.z; tileF[c][h8 + q * 4 + 3] = v.w;
            }
        }
        __syncthreads();
        {
            const int hw = t >> 3, i8 = (t & 7) * 8;
            __align__(16) ushort o8[8];
            #pragma unroll
            for (int k = 0; k < 8; ++k) o8[k] = f2bf(tileF[i8 + k][hw]);
            *(int4*)&Bls[hw][i8] = *(const int4*)o8;
        }
        __syncthreads();
        #pragma unroll
        for (int kk = 0; kk < 2; ++kk) {
            bf16x8 af[4];
            const int fb = ((kc * 2 + kk) * 16 + w * 4) * 512 + lane * 8;
            #pragma unroll
            for (int rf = 0; rf < 4; ++rf)
                af[rf] = *(const bf16x8*)(Wv16 + fb + rf * 512);
            #pragma unroll
            for (int cf = 0; cf < 2; ++cf) {
                bf16x8 bf_ = *(const bf16x8*)&Bls[cf * 16 + (lane & 15)]
                                                 [kk * 32 + (lane >> 4) * 8];
                #pragma unroll
                for (int rf = 0; rf < 4; ++rf)
                    acc[rf][cf] = __builtin_amdgcn_mfma_f32_16x16x32_bf16(
                        af[rf], bf_, acc[rf][cf], 0, 0, 0);
            }
        }
    }
    #pragma unroll
    for (int rf = 0; rf < 4; ++rf) {
        const int ob = w * 64 + rf * 16 + (lane >> 4) * 4;
        #pragma unroll
        for (int cf = 0; cf < 2; ++cf) {
            const int hw = hw0 + cf * 16 + (lane & 15);
            const float mv = m2s[ob >> 2];
            #pragma unroll
            for (int r = 0; r < 4; ++r) {   // o = ob+r, o%4 == r
                float vv = acc[rf][cf][r] + bv[ob + r];
                float qm = finv(qmkey[r * HW + hw]);
                outf[((size_t)b * CH + ob + r) * HW + hw] = vv * (1.0f + mv * qm);
            }
        }
    }
}

// ---------------------------------------------------------------------------
// scores64 persistent m-strip. R18: BK/AQ loads are INLINE-ASM
// global_load_dwordx4 -- not rematerializable, so the allocator MUST keep
// them in VGPRs (R15-R17: compiler pinned VGPR at 124 and re-issued the Q
// loads, FETCH +50%). Explicit vmcnt(0)+sched_barrier before each MFMA
// block (rule #18); prefetch of Q(it+1) issues after the MFMAs and stays in
// flight across the raw lgkmcnt-only barriers of the EX epilogue.
__global__ __launch_bounds__(256)
__attribute__((amdgpu_waves_per_eu(2, 2))) void scores64(
    const u8* __restrict__ Qw, const u8* __restrict__ Kw,
    unsigned int* __restrict__ m2k) {
    __shared__ __align__(16) f32x4 EX[4][4][4][64];   // [b][nf][mf][lane] 64 KB
    __shared__ float red[4][4];                       // [wave][batch]
    const int t = threadIdx.x;
    const int lane = t & 63, w = t >> 6;              // w = batch
    const int bid = blockIdx.x;
    const int xcd = bid & 7, j = bid >> 3;
    const int vm = xcd * 8 + (j & 7);
    const int s  = j >> 3;                            // n-strip: vn = s*8+it

    const u8* kp  = Kw + (((size_t)w * 8) * 128 + vm * 2) * 1024 + lane * 16;
    const u8* qp0 = Qw + (((size_t)w * 8) * 128 + (s * 8) * 2) * 1024 + lane * 16;

    // K resident for the whole strip (asm loads -> forced materialization)
    longx2 BK[8][2];
    #pragma unroll
    for (int kc = 0; kc < 8; ++kc)
        #pragma unroll
        for (int p = 0; p < 2; ++p)
            gload16(BK[kc][p], kp + (size_t)kc * 131072 + p * 1024);

    longx2 AQ[8][2];
#define LOADQ(IT)                                                          \
    _Pragma("unroll") for (int kc = 0; kc < 8; ++kc)                       \
        _Pragma("unroll") for (int p = 0; p < 2; ++p)                      \
            gload16(AQ[kc][p], qp0 + (IT) * 2048                           \
                               + (size_t)kc * 131072 + p * 1024);
    LOADQ(0)

    float pmAll[4] = {0.f, 0.f, 0.f, 0.f};
    #pragma unroll
    for (int it = 0; it < 8; ++it) {
        // wait for AQ(it) (and BK on it=0); vmcnt counts ONLY our asm loads
        asm volatile("s_waitcnt vmcnt(0)" ::: "memory");
        __builtin_amdgcn_sched_barrier(0);   // rule #18: pin MFMAs after wait

        f32x4 acc[4][4] = {};   // [nf][mf]
        #pragma unroll
        for (int kc = 0; kc < 8; ++kc) {
            #pragma unroll
            for (int mf = 0; mf < 4; ++mf) {
                long bf_ = BK[kc][mf >> 1][mf & 1];
                #pragma unroll
                for (int nf = 0; nf < 4; ++nf)
                    acc[nf][mf] = __builtin_amdgcn_mfma_f32_16x16x32_fp8_fp8(
                        AQ[kc][nf >> 1][nf & 1], bf_, acc[nf][mf], 0, 0, 0);
            }
        }
        __builtin_amdgcn_sched_barrier(0);   // MFMAs read AQ before re-issue

        // prefetch next tile's Q; stays in flight across the raw barriers
        if (it + 1 < 8) { LOADQ(it + 1) }

        if (it) LGK_BAR();                // prev tile's EX reads done everywhere
        #pragma unroll
        for (int nf = 0; nf < 4; ++nf)
            #pragma unroll
            for (int mf = 0; mf < 4; ++mf)
                EX[w][nf][mf][lane] = acc[nf][mf];
        LGK_BAR();                        // all EX writes visible
        #pragma unroll
        for (int nf = 0; nf < 4; ++nf) {
            f32x4 sv[4];
            #pragma unroll
            for (int b2 = 0; b2 < 4; ++b2)
                sv[b2] = EX[b2][nf][w][lane];   // this thread owns mf = w
            #pragma unroll
            for (int jj = 0; jj < 4; ++jj) {
                float e0 = __expf(sv[0][jj] * 0.0625f);
                float e1 = __expf(sv[1][jj] * 0.0625f);
                float e2 = __expf(sv[2][jj] * 0.0625f);
                float e3 = __expf(sv[3][jj] * 0.0625f);
                float inv = __fdividef(1.0f, e0 + e1 + e2 + e3);
                pmAll[0] = fmaxf(pmAll[0], e0 * inv);
                pmAll[1] = fmaxf(pmAll[1], e1 * inv);
                pmAll[2] = fmaxf(pmAll[2], e2 * inv);
                pmAll[3] = fmaxf(pmAll[3], e3 * inv);
            }
        }
    }
#undef LOADQ
    // strip-wide reduce: wave max, block max, ONE atomic per batch
    #pragma unroll
    for (int off = 32; off >= 1; off >>= 1) {
        pmAll[0] = fmaxf(pmAll[0], __shfl_xor(pmAll[0], off));
        pmAll[1] = fmaxf(pmAll[1], __shfl_xor(pmAll[1], off));
        pmAll[2] = fmaxf(pmAll[2], __shfl_xor(pmAll[2], off));
        pmAll[3] = fmaxf(pmAll[3], __shfl_xor(pmAll[3], off));
    }
    __syncthreads();
    if (lane == 0) {
        #pragma unroll
        for (int b2 = 0; b2 < 4; ++b2) red[w][b2] = pmAll[b2];
    }
    __syncthreads();
    if (t < 4) {   // t = batch
        float v = fmaxf(fmaxf(red[0][t], red[1][t]),
                        fmaxf(red[2][t], red[3][t]));
        atomicMax(m2k + t * 64 + vm, __float_as_uint(v));  // soft > 0
    }
}

// ---------------------------------------------------------------------------
extern "C" void kernel_launch(void* const* d_in, const int* in_sizes, int n_in,
                              void* d_out, int out_size, void* d_ws, size_t ws_size,
                              hipStream_t stream) {
    const float* fuse = (const float*)d_in[0];
    const float* Wq   = (const float*)d_in[1];
    const float* bq   = (const float*)d_in[2];
    const float* Wk   = (const float*)d_in[3];
    const float* bk   = (const float*)d_in[4];
    const float* Wv   = (const float*)d_in[5];
    const float* bv   = (const float*)d_in[6];
    float* out = (float*)d_out;

    char* ws = (char*)d_ws;
    ushort* Wq16  = (ushort*)(ws);                      // 128 KiB (A-frag packed)
    ushort* Wk16  = (ushort*)(ws + 131072);             // 128 KiB
    ushort* Wv16  = (ushort*)(ws + 262144);             // 128 KiB
    u8*     Qw8   = (u8*)    (ws + 393216);             // 4 MiB (fp8 pair-frag)
    u8*     Kw8   = (u8*)    (ws + 4587520);            // 4 MiB (fp8 pair-frag)
    unsigned int* QMK = (unsigned int*)(ws + 8781824);  // 64 KiB (Q_mask keys)
    unsigned int* M2K = (unsigned int*)(ws + 8847360);  // 1 KiB (m2 keys)

    prep_kernel<<<256, 256, 0, stream>>>(Wq, Wk, Wv, Wq16, Wk16, Wv16, M2K, QMK);
    convQK_kernel<<<dim3(128, NB), 256, 0, stream>>>(
        fuse, Wq16, Wk16, bq, bk, Qw8, Kw8, QMK);
    scores64<<<512, 256, 0, stream>>>(Qw8, Kw8, M2K);
    convV_kernel<<<dim3(128, NB), 256, 0, stream>>>(
        fuse, Wv16, bv, out, M2K, QMK);
}